// Round 13
// baseline (281.138 us; speedup 1.0000x reference)
//
#include <hip/hip_runtime.h>
#include <cstddef>
#include <cstdint>

#define NN   100000   // nodes
#define NR   4        // relations
#define NE   160000   // edges per relation
#define SCAN_B 1024
#define GEMMB1 256    // dual-relation gemm blocks in phaseB (128 vblocks x 2 pairs)

typedef short bf16x8 __attribute__((ext_vector_type(8)));
typedef float f32x4  __attribute__((ext_vector_type(4)));

__device__ __forceinline__ unsigned short f2bf(float f) {  // RNE f32->bf16
  union { float f; unsigned u; } v; v.f = f;
  unsigned r = v.u + 0x7fffu + ((v.u >> 16) & 1u);
  return (unsigned short)(r >> 16);
}
__device__ __forceinline__ float bf2f(unsigned short h) {
  union { unsigned u; float f; } v; v.u = ((unsigned)h) << 16;
  return v.f;
}

// async global->LDS, 16B per lane, linear LDS dest
__device__ __forceinline__ void gll16(const unsigned short* g, unsigned short* l) {
  __builtin_amdgcn_global_load_lds(
      (const __attribute__((address_space(1))) void*)g,
      (__attribute__((address_space(3))) void*)l, 16, 0, 0);
}

// ---------------------------------------------------------------- converts (standalone)
// [0,6250): cvtx | [6250,6506): cvtw1 | [6506,6634): cvtw2 | [6634]: bias
#define CVT_NBLK 6635
__global__ __launch_bounds__(256) void cvtA_k(const float* __restrict__ x,
                                              const float* __restrict__ W1,
                                              const float* __restrict__ W2,
                                              const float* __restrict__ b1,
                                              const float* __restrict__ b2,
                                              unsigned short* __restrict__ xb,
                                              unsigned short* __restrict__ Wt1,
                                              unsigned short* __restrict__ Wt2,
                                              float* __restrict__ bs1,
                                              float* __restrict__ bs2) {
  const int bid = blockIdx.x;
  const int t = threadIdx.x;
  if (bid < 6250) {  // cvtx: 6250*256*8 == NN*128
    const int i = bid * 256 + t;
    const float4 a = *(const float4*)&x[(size_t)i * 8];
    const float4 b = *(const float4*)&x[(size_t)i * 8 + 4];
    unsigned short o[8];
    o[0] = f2bf(a.x); o[1] = f2bf(a.y); o[2] = f2bf(a.z); o[3] = f2bf(a.w);
    o[4] = f2bf(b.x); o[5] = f2bf(b.y); o[6] = f2bf(b.z); o[7] = f2bf(b.w);
    *(bf16x8*)&xb[(size_t)i * 8] = *(bf16x8*)o;
  } else if (bid < 6506) {  // cvtw1: 65536 == NR*128*128
    const int i = (bid - 6250) * 256 + t;
    const int r = i / (128 * 128);
    const int k = (i / 128) % 128;
    const int n = i % 128;
    Wt1[((size_t)r * 128 + n) * 128 + k] = f2bf(W1[i]);
  } else if (bid < 6634) {  // cvtw2: 32768 == NR*128*64
    const int i = (bid - 6506) * 256 + t;
    const int r = i / (128 * 64);
    const int k = (i / 64) % 128;
    const int n = i % 64;
    Wt2[((size_t)r * 64 + n) * 128 + k] = f2bf(W2[i]);
  } else {
    if (t < 128) bs1[t] = b1[t] + b1[128 + t] + b1[256 + t] + b1[384 + t];
    if (t < 64)  bs2[t] = b2[t] + b2[64 + t] + b2[128 + t] + b2[192 + t];
  }
}

// ---------------------------------------------------------------- dual-relation GEMM core
// Two relations share one staged X tile. NOUT=128: NF=4/rel; NOUT=64: NF=2/rel.
template <int NOUT>
__device__ __forceinline__ void gemm_dual_core(const unsigned short* __restrict__ Xb,
                                               const unsigned short* __restrict__ W0,
                                               const unsigned short* __restrict__ W1,
                                               unsigned short* __restrict__ H0,
                                               unsigned short* __restrict__ H1,
                                               int vb, unsigned short (*Xl)[64 * 128]) {
  const int t = threadIdx.x;
  const int wid = t >> 6;
  const int lane = t & 63;
  const int lg = lane >> 4;
  const int lr = lane & 15;

  constexpr int NF = NOUT / 32;              // frags per relation per wave
  const int rbase = (wid & 1) * 32;
  const int cbase = (wid >> 1) * (NOUT / 2);

  bf16x8 bw[2][NF][4];  // [rel][nf][ks]
#pragma unroll
  for (int nf = 0; nf < NF; ++nf)
#pragma unroll
    for (int ks = 0; ks < 4; ++ks) {
      bw[0][nf][ks] = *(const bf16x8*)&W0[(size_t)(cbase + nf * 16 + lr) * 128 + ks * 32 + lg * 8];
      bw[1][nf][ks] = *(const bf16x8*)&W1[(size_t)(cbase + nf * 16 + lr) * 128 + ks * 32 + lg * 8];
    }

  auto stage = [&](int buf, int tile) {
    const int row0 = tile * 64;
#pragma unroll
    for (int i = 0; i < 4; ++i) {
      const int rl = wid * 16 + i * 4 + (lane >> 4);
      int gr = row0 + rl;
      if (gr >= NN) gr = NN - 1;
      const int q = (lane & 15) ^ (rl & 7);
      gll16(&Xb[(size_t)gr * 128 + q * 8], &Xl[buf][rl * 128 + (lane & 15) * 8]);
    }
  };

  const int ntiles = (NN + 63) / 64;  // 1563
  int tile = vb;
  stage(0, tile);
  __syncthreads();
  int buf = 0;

  for (; tile < ntiles; tile += 128) {
    const int nxt = tile + 128;
    if (nxt < ntiles) stage(buf ^ 1, nxt);

    f32x4 acc[2][2][NF];  // [mf][rel][nf]
#pragma unroll
    for (int mf = 0; mf < 2; ++mf)
#pragma unroll
      for (int rel = 0; rel < 2; ++rel)
#pragma unroll
        for (int nf = 0; nf < NF; ++nf) acc[mf][rel][nf] = (f32x4){0.f, 0.f, 0.f, 0.f};

#pragma unroll
    for (int ks = 0; ks < 4; ++ks) {
#pragma unroll
      for (int mf = 0; mf < 2; ++mf) {
        const int r = rbase + mf * 16 + lr;
        const bf16x8 a =
            *(const bf16x8*)&Xl[buf][r * 128 + (((ks * 4 + lg) ^ (lr & 7)) << 3)];
#pragma unroll
        for (int rel = 0; rel < 2; ++rel)
#pragma unroll
          for (int nf = 0; nf < NF; ++nf)
            acc[mf][rel][nf] = __builtin_amdgcn_mfma_f32_16x16x32_bf16(a, bw[rel][nf][ks], acc[mf][rel][nf], 0, 0, 0);
      }
    }

    const int row0 = tile * 64;
#pragma unroll
    for (int mf = 0; mf < 2; ++mf) {
#pragma unroll
      for (int i = 0; i < 4; ++i) {
        const int row = row0 + rbase + mf * 16 + lg * 4 + i;
        if (row < NN) {
#pragma unroll
          for (int nf = 0; nf < NF; ++nf) {
            H0[(size_t)row * NOUT + cbase + nf * 16 + lr] = f2bf(acc[mf][0][nf][i]);
            H1[(size_t)row * NOUT + cbase + nf * 16 + lr] = f2bf(acc[mf][1][nf][i]);
          }
        }
      }
    }
    __syncthreads();
    buf ^= 1;
  }
}

// ---------------------------------------------------------------- phase B: dual gemm1 || count
// [0,GEMMB1): dual gemm, pair zp=bid>>7, vblock bid&127 | [GEMMB1,GEMMB1+2500): count
__global__ __launch_bounds__(256, 2) void phaseB_k(const int* __restrict__ edges,
                                                   const unsigned short* __restrict__ xb,
                                                   const unsigned short* __restrict__ Wt1,
                                                   unsigned short* __restrict__ H,
                                                   int* __restrict__ cnt_out,
                                                   int* __restrict__ cnt_in) {
  __shared__ unsigned short Xl[2][64 * 128];  // 32 KB
  const int bid = blockIdx.x;
  if (bid < GEMMB1) {
    const int zp = bid >> 7;
    gemm_dual_core<128>(xb,
                        Wt1 + (size_t)(2 * zp) * 128 * 128,
                        Wt1 + (size_t)(2 * zp + 1) * 128 * 128,
                        H + (size_t)(2 * zp) * NN * 128,
                        H + (size_t)(2 * zp + 1) * NN * 128,
                        bid & 127, Xl);
    return;
  }
  const int idx = bid - GEMMB1;
  const int r = idx / 625;
  const int e = (idx - r * 625) * 256 + threadIdx.x;
  const int s = edges[(size_t)r * 2 * NE + e];
  const int d = edges[(size_t)r * 2 * NE + NE + e];
  atomicAdd(&cnt_out[(size_t)r * NN + s], 1);
  atomicAdd(&cnt_in[(size_t)r * NN + d], 1);
}

// ---------------------------------------------------------------- layer-2 dual GEMM
__global__ __launch_bounds__(256, 2) void gemm_dual_k(const unsigned short* __restrict__ Xb,
                                                      const unsigned short* __restrict__ Wt,
                                                      unsigned short* __restrict__ H) {
  __shared__ unsigned short Xl[2][64 * 128];
  const int zp = blockIdx.z;
  gemm_dual_core<64>(Xb,
                     Wt + (size_t)(2 * zp) * 64 * 128,
                     Wt + (size_t)(2 * zp + 1) * 64 * 128,
                     H + (size_t)(2 * zp) * NN * 64,
                     H + (size_t)(2 * zp + 1) * NN * 64,
                     blockIdx.x, Xl);
}

// ---------------------------------------------------------------- scans (verbatim)
__global__ __launch_bounds__(256) void scan1_k(const int* __restrict__ cnt_in,
                                               int* __restrict__ excl,
                                               int* __restrict__ bsum) {
  const int b = blockIdx.x, t = threadIdx.x;
  const int base = b * SCAN_B;
  int v[4]; int tl = 0;
#pragma unroll
  for (int i = 0; i < 4; ++i) {
    const int idx = base + t * 4 + i;
    int c = 0;
    if (idx < NN) {
      c = cnt_in[idx] + cnt_in[NN + idx] + cnt_in[2 * NN + idx] + cnt_in[3 * NN + idx];
    }
    v[i] = c;
    tl += c;
  }
  __shared__ int sm[256];
  sm[t] = tl;
  __syncthreads();
  for (int off = 1; off < 256; off <<= 1) {
    const int x = (t >= off) ? sm[t - off] : 0;
    __syncthreads();
    sm[t] += x;
    __syncthreads();
  }
  const int incl = sm[t];
  int run = incl - tl;
#pragma unroll
  for (int i = 0; i < 4; ++i) {
    const int idx = base + t * 4 + i;
    if (idx < NN) excl[idx] = run;
    run += v[i];
  }
  if (t == 255) bsum[b] = incl;
}

__global__ __launch_bounds__(128) void scan2_k(int* __restrict__ bsum, int nb) {
  const int t = threadIdx.x;
  __shared__ int sm[128];
  const int v = (t < nb) ? bsum[t] : 0;
  sm[t] = v;
  __syncthreads();
  for (int off = 1; off < 128; off <<= 1) {
    const int x = (t >= off) ? sm[t - off] : 0;
    __syncthreads();
    sm[t] += x;
    __syncthreads();
  }
  if (t < nb) bsum[t] = sm[t] - v;
}

// scan3 + rs merged: [0,3125): rs over 2*NR*NN; [3125,...): scan3
__global__ __launch_bounds__(256) void scan3rs_k(const int* __restrict__ cnt,
                                                 float* __restrict__ rs,
                                                 const int* __restrict__ bsum,
                                                 int* __restrict__ row_ptr,
                                                 int* __restrict__ cursor) {
  const int bid = blockIdx.x, t = threadIdx.x;
  if (bid < 3125) {
    const int i = bid * 256 + t;
    rs[i] = rsqrtf(fmaxf((float)cnt[i], 1.0f));
  } else {
    const int i = (bid - 3125) * 256 + t;
    if (i < NN) {
      const int v = cursor[i] + bsum[i / SCAN_B];  // cursor holds excl from scan1
      row_ptr[i] = v;
      cursor[i] = v;
    }
    if (i == 0) row_ptr[NN] = NR * NE;
  }
}

// ---------------------------------------------------------------- fill (combined edge weight)
__global__ __launch_bounds__(256) void fill_k(const int* __restrict__ edges,
                                              const float* __restrict__ rs_out,
                                              const float* __restrict__ rs_in,
                                              int* __restrict__ cursor,
                                              int2* __restrict__ csr) {
  const int r = blockIdx.y;
  const int e = blockIdx.x * 256 + threadIdx.x;
  if (e >= NE) return;
  const int s = edges[(size_t)r * 2 * NE + e];
  const int d = edges[(size_t)r * 2 * NE + NE + e];
  const int pos = atomicAdd(&cursor[d], 1);
  const float w = rs_in[(size_t)r * NN + d] * rs_out[(size_t)r * NN + s];
  csr[pos] = make_int2(r * NN + s, __float_as_int(w));
}

// ---------------------------------------------------------------- gathers (R10-proven shapes)
__global__ __launch_bounds__(256) void gather1_k(const unsigned short* __restrict__ H,
                                                 const int* __restrict__ row_ptr,
                                                 const int2* __restrict__ csr,
                                                 const float* __restrict__ bs1,
                                                 unsigned short* __restrict__ h1b) {
  const int node = blockIdx.x * 4 + (threadIdx.x >> 6);
  const int lane = threadIdx.x & 63;
  if (node >= NN) return;
  const int g  = lane >> 4;
  const int fl = lane & 15;

  float acc[8];
#pragma unroll
  for (int j = 0; j < 8; ++j) acc[j] = 0.f;

  const int beg = row_ptr[node];
  const int end = row_ptr[node + 1];
  for (int e = beg + g; e < end; e += 4) {
    const int2 p = csr[e];
    const float w = __int_as_float(p.y);
    const bf16x8 h = *(const bf16x8*)&H[(size_t)p.x * 128 + fl * 8];
#pragma unroll
    for (int j = 0; j < 8; ++j)
      acc[j] = fmaf(bf2f((unsigned short)h[j]), w, acc[j]);
  }
#pragma unroll
  for (int j = 0; j < 8; ++j) {
    acc[j] += __shfl_xor(acc[j], 16);
    acc[j] += __shfl_xor(acc[j], 32);
  }
  if (g == 0) {
    const float4 c0 = *(const float4*)&bs1[fl * 8];
    const float4 c1 = *(const float4*)&bs1[fl * 8 + 4];
    unsigned short o[8];
    o[0] = f2bf(fmaxf(acc[0] + c0.x, 0.f));
    o[1] = f2bf(fmaxf(acc[1] + c0.y, 0.f));
    o[2] = f2bf(fmaxf(acc[2] + c0.z, 0.f));
    o[3] = f2bf(fmaxf(acc[3] + c0.w, 0.f));
    o[4] = f2bf(fmaxf(acc[4] + c1.x, 0.f));
    o[5] = f2bf(fmaxf(acc[5] + c1.y, 0.f));
    o[6] = f2bf(fmaxf(acc[6] + c1.z, 0.f));
    o[7] = f2bf(fmaxf(acc[7] + c1.w, 0.f));
    *(bf16x8*)&h1b[(size_t)node * 128 + fl * 8] = *(bf16x8*)o;
  }
}

__global__ __launch_bounds__(256) void gather2_k(const unsigned short* __restrict__ H,
                                                 const int* __restrict__ row_ptr,
                                                 const int2* __restrict__ csr,
                                                 const float* __restrict__ bs2,
                                                 float* __restrict__ out) {
  const int node = blockIdx.x * 4 + (threadIdx.x >> 6);
  const int lane = threadIdx.x & 63;
  if (node >= NN) return;
  const int g  = lane >> 3;
  const int fl = lane & 7;

  float acc[8];
#pragma unroll
  for (int j = 0; j < 8; ++j) acc[j] = 0.f;

  const int beg = row_ptr[node];
  const int end = row_ptr[node + 1];
  for (int e = beg + g; e < end; e += 8) {
    const int2 p = csr[e];
    const float w = __int_as_float(p.y);
    const bf16x8 h = *(const bf16x8*)&H[(size_t)p.x * 64 + fl * 8];
#pragma unroll
    for (int j = 0; j < 8; ++j)
      acc[j] = fmaf(bf2f((unsigned short)h[j]), w, acc[j]);
  }
#pragma unroll
  for (int j = 0; j < 8; ++j) {
    acc[j] += __shfl_xor(acc[j], 8);
    acc[j] += __shfl_xor(acc[j], 16);
    acc[j] += __shfl_xor(acc[j], 32);
  }
  if (g == 0) {
    const float4 c0 = *(const float4*)&bs2[fl * 8];
    const float4 c1 = *(const float4*)&bs2[fl * 8 + 4];
    float4 o0, o1;
    o0.x = acc[0] + c0.x; o0.y = acc[1] + c0.y; o0.z = acc[2] + c0.z; o0.w = acc[3] + c0.w;
    o1.x = acc[4] + c1.x; o1.y = acc[5] + c1.y; o1.z = acc[6] + c1.z; o1.w = acc[7] + c1.w;
    *(float4*)&out[(size_t)node * 64 + fl * 8]     = o0;
    *(float4*)&out[(size_t)node * 64 + fl * 8 + 4] = o1;
  }
}

// ---------------------------------------------------------------- launch
extern "C" void kernel_launch(void* const* d_in, const int* in_sizes, int n_in,
                              void* d_out, int out_size, void* d_ws, size_t ws_size,
                              hipStream_t stream) {
  const float* x     = (const float*)d_in[0];
  const int*   edges = (const int*)d_in[1];
  const float* W1    = (const float*)d_in[2];
  const float* b1    = (const float*)d_in[3];
  const float* W2    = (const float*)d_in[4];
  const float* b2    = (const float*)d_in[5];
  float* out = (float*)d_out;

  // ---- workspace layout (proven footprint)
  unsigned short* xb   = (unsigned short*)d_ws;            // NN*128 bf16
  unsigned short* h1b  = xb;                               // reuse after layer1 GEMM
  unsigned short* Hbuf = xb + (size_t)NN * 128;            // NR*NN*128 bf16
  unsigned short* Wt1  = Hbuf + (size_t)NR * NN * 128;     // NR*128*128 bf16
  unsigned short* Wt2  = Wt1 + (size_t)NR * 128 * 128;     // NR*64*128 bf16
  float* rs_out = (float*)(Wt2 + (size_t)NR * 64 * 128);   // NR*NN
  float* rs_in  = rs_out + (size_t)NR * NN;                // NR*NN
  int* cnt_out  = (int*)(rs_in + (size_t)NR * NN);         // NR*NN
  int* cnt_in   = cnt_out + (size_t)NR * NN;               // NR*NN
  int* row_ptr  = cnt_in + (size_t)NR * NN;                // NN+1
  int* cursor   = row_ptr + (NN + 1);                      // NN
  int* bsum     = cursor + NN;                             // 128
  float* bs1    = (float*)(bsum + 128);                    // 128
  float* bs2    = bs1 + 128;                               // 64
  int2* csr     = (int2*)(bs2 + 64);                       // NR*NE int2

  const int nb = (NN + SCAN_B - 1) / SCAN_B;  // 98

  // 1) zero counters
  hipMemsetAsync(cnt_out, 0, (size_t)2 * NR * NN * sizeof(int), stream);
  // 2) converts standalone (pairing with count costs more than it saves)
  cvtA_k<<<CVT_NBLK, 256, 0, stream>>>(x, W1, W2, b1, b2, xb, Wt1, Wt2, bs1, bs2);
  // 3) dual-relation layer-1 GEMM co-resident with count atomics (proven pairing)
  phaseB_k<<<GEMMB1 + 2500, 256, 0, stream>>>(edges, xb, Wt1, Hbuf, cnt_out, cnt_in);
  // 4-6) scans + rs arrays
  scan1_k<<<nb, 256, 0, stream>>>(cnt_in, cursor /*excl temp*/, bsum);
  scan2_k<<<1, 128, 0, stream>>>(bsum, nb);
  scan3rs_k<<<3125 + (NN + 255) / 256, 256, 0, stream>>>(cnt_out, rs_out, bsum, row_ptr, cursor);
  // 7) CSR fill with combined edge weights
  fill_k<<<dim3((NE + 255) / 256, NR), 256, 0, stream>>>(edges, rs_out, rs_in, cursor, csr);
  // 8) gather+bias+relu -> h1b
  gather1_k<<<(NN + 3) / 4, 256, 0, stream>>>(Hbuf, row_ptr, csr, bs1, h1b);
  // 9) layer-2 dual GEMM
  gemm_dual_k<<<dim3(128, 1, 2), 256, 0, stream>>>(h1b, Wt2, Hbuf);
  // 10) gather+bias -> out
  gather2_k<<<(NN + 3) / 4, 256, 0, stream>>>(Hbuf, row_ptr, csr, bs2, out);
}

// Round 14
// 217.056 us; speedup vs baseline: 1.2952x; 1.2952x over previous
//
#include <hip/hip_runtime.h>
#include <cstddef>
#include <cstdint>

#define NN   100000   // nodes
#define NR   4        // relations
#define NE   160000   // edges per relation
#define SCAN_B 1024
#define GEMMB 512     // gemm virtual blocks in phaseB (128 per relation)

typedef short bf16x8 __attribute__((ext_vector_type(8)));
typedef float f32x4  __attribute__((ext_vector_type(4)));

__device__ __forceinline__ unsigned short f2bf(float f) {  // RNE f32->bf16
  union { float f; unsigned u; } v; v.f = f;
  unsigned r = v.u + 0x7fffu + ((v.u >> 16) & 1u);
  return (unsigned short)(r >> 16);
}
__device__ __forceinline__ float bf2f(unsigned short h) {
  union { unsigned u; float f; } v; v.u = ((unsigned)h) << 16;
  return v.f;
}

// async global->LDS, 16B per lane, linear LDS dest
__device__ __forceinline__ void gll16(const unsigned short* g, unsigned short* l) {
  __builtin_amdgcn_global_load_lds(
      (const __attribute__((address_space(1))) void*)g,
      (__attribute__((address_space(3))) void*)l, 16, 0, 0);
}

// ---------------------------------------------------------------- phase A (R10 verbatim: zero + converts)
// [0,782): zero cnt arrays (int4) | [782,7032): cvtx | [7032,7288): cvtw1
// [7288,7416): cvtw2 | [7416]: bias sums
#define A_ZERO 782
#define A_NBLK (A_ZERO + 6250 + 256 + 128 + 1)  // 7417
__global__ __launch_bounds__(256) void phaseA_k(const float* __restrict__ x,
                                                const float* __restrict__ W1,
                                                const float* __restrict__ W2,
                                                const float* __restrict__ b1,
                                                const float* __restrict__ b2,
                                                int* __restrict__ cnt,      // cnt_out|cnt_in, 2*NR*NN ints
                                                unsigned short* __restrict__ xb,
                                                unsigned short* __restrict__ Wt1,
                                                unsigned short* __restrict__ Wt2,
                                                float* __restrict__ bs1,
                                                float* __restrict__ bs2) {
  const int bid = blockIdx.x;
  const int t = threadIdx.x;
  if (bid < A_ZERO) {  // zero 800000 ints as int4
    const int i = bid * 256 + t;
    if (i < 2 * NR * NN / 4) ((int4*)cnt)[i] = make_int4(0, 0, 0, 0);
  } else if (bid < A_ZERO + 6250) {  // cvtx
    const int i = (bid - A_ZERO) * 256 + t;
    const float4 a = *(const float4*)&x[(size_t)i * 8];
    const float4 b = *(const float4*)&x[(size_t)i * 8 + 4];
    unsigned short o[8];
    o[0] = f2bf(a.x); o[1] = f2bf(a.y); o[2] = f2bf(a.z); o[3] = f2bf(a.w);
    o[4] = f2bf(b.x); o[5] = f2bf(b.y); o[6] = f2bf(b.z); o[7] = f2bf(b.w);
    *(bf16x8*)&xb[(size_t)i * 8] = *(bf16x8*)o;
  } else if (bid < A_ZERO + 6250 + 256) {  // cvtw1
    const int i = (bid - A_ZERO - 6250) * 256 + t;
    const int r = i / (128 * 128);
    const int k = (i / 128) % 128;
    const int n = i % 128;
    Wt1[((size_t)r * 128 + n) * 128 + k] = f2bf(W1[i]);
  } else if (bid < A_ZERO + 6250 + 256 + 128) {  // cvtw2
    const int i = (bid - A_ZERO - 6250 - 256) * 256 + t;
    const int r = i / (128 * 64);
    const int k = (i / 64) % 128;
    const int n = i % 64;
    Wt2[((size_t)r * 64 + n) * 128 + k] = f2bf(W2[i]);
  } else {
    if (t < 128) bs1[t] = b1[t] + b1[128 + t] + b1[256 + t] + b1[384 + t];
    if (t < 64)  bs2[t] = b2[t] + b2[64 + t] + b2[128 + t] + b2[192 + t];
  }
}

// ---------------------------------------------------------------- GEMM core (R10 verbatim; 64-row tiles, unscaled)
template <int NOUT>
__device__ __forceinline__ void gemm_core(const unsigned short* __restrict__ Xb,
                                          const unsigned short* __restrict__ Wtr,
                                          unsigned short* __restrict__ Hr,
                                          int vb, unsigned short (*Xl)[64 * 128]) {
  const int t = threadIdx.x;
  const int wid = t >> 6;
  const int lane = t & 63;
  const int lg = lane >> 4;
  const int lr = lane & 15;

  constexpr int NF = (NOUT == 128) ? 4 : 2;
  const int rbase = (wid & 1) * 32;
  const int cbase = (wid >> 1) * (NOUT / 2);

  bf16x8 bw[NF][4];
#pragma unroll
  for (int nf = 0; nf < NF; ++nf)
#pragma unroll
    for (int ks = 0; ks < 4; ++ks)
      bw[nf][ks] = *(const bf16x8*)&Wtr[(size_t)(cbase + nf * 16 + lr) * 128 + ks * 32 + lg * 8];

  auto stage = [&](int buf, int tile) {
    const int row0 = tile * 64;
#pragma unroll
    for (int i = 0; i < 4; ++i) {
      const int rl = wid * 16 + i * 4 + (lane >> 4);
      int gr = row0 + rl;
      if (gr >= NN) gr = NN - 1;
      const int q = (lane & 15) ^ (rl & 7);
      gll16(&Xb[(size_t)gr * 128 + q * 8], &Xl[buf][rl * 128 + (lane & 15) * 8]);
    }
  };

  const int ntiles = (NN + 63) / 64;  // 1563
  int tile = vb;
  stage(0, tile);
  __syncthreads();
  int buf = 0;

  for (; tile < ntiles; tile += 128) {
    const int nxt = tile + 128;
    if (nxt < ntiles) stage(buf ^ 1, nxt);

    f32x4 acc[2][NF];
#pragma unroll
    for (int mf = 0; mf < 2; ++mf)
#pragma unroll
      for (int nf = 0; nf < NF; ++nf) acc[mf][nf] = (f32x4){0.f, 0.f, 0.f, 0.f};

#pragma unroll
    for (int ks = 0; ks < 4; ++ks) {
#pragma unroll
      for (int mf = 0; mf < 2; ++mf) {
        const int r = rbase + mf * 16 + lr;
        const bf16x8 a =
            *(const bf16x8*)&Xl[buf][r * 128 + (((ks * 4 + lg) ^ (lr & 7)) << 3)];
#pragma unroll
        for (int nf = 0; nf < NF; ++nf)
          acc[mf][nf] = __builtin_amdgcn_mfma_f32_16x16x32_bf16(a, bw[nf][ks], acc[mf][nf], 0, 0, 0);
      }
    }

    const int row0 = tile * 64;
#pragma unroll
    for (int mf = 0; mf < 2; ++mf) {
#pragma unroll
      for (int i = 0; i < 4; ++i) {
        const int row = row0 + rbase + mf * 16 + lg * 4 + i;
        if (row < NN) {
#pragma unroll
          for (int nf = 0; nf < NF; ++nf)
            Hr[(size_t)row * NOUT + cbase + nf * 16 + lr] = f2bf(acc[mf][nf][i]);
        }
      }
    }
    __syncthreads();
    buf ^= 1;
  }
}

// ---------------------------------------------------------------- dual-relation GEMM core (NOUT=64 only; register-safe)
__device__ __forceinline__ void gemm_dual_core64(const unsigned short* __restrict__ Xb,
                                                 const unsigned short* __restrict__ W0,
                                                 const unsigned short* __restrict__ W1,
                                                 unsigned short* __restrict__ H0,
                                                 unsigned short* __restrict__ H1,
                                                 int vb, unsigned short (*Xl)[64 * 128]) {
  const int t = threadIdx.x;
  const int wid = t >> 6;
  const int lane = t & 63;
  const int lg = lane >> 4;
  const int lr = lane & 15;

  const int rbase = (wid & 1) * 32;
  const int cbase = (wid >> 1) * 32;

  bf16x8 bw[2][2][4];  // [rel][nf][ks] = 64 VGPR
#pragma unroll
  for (int nf = 0; nf < 2; ++nf)
#pragma unroll
    for (int ks = 0; ks < 4; ++ks) {
      bw[0][nf][ks] = *(const bf16x8*)&W0[(size_t)(cbase + nf * 16 + lr) * 128 + ks * 32 + lg * 8];
      bw[1][nf][ks] = *(const bf16x8*)&W1[(size_t)(cbase + nf * 16 + lr) * 128 + ks * 32 + lg * 8];
    }

  auto stage = [&](int buf, int tile) {
    const int row0 = tile * 64;
#pragma unroll
    for (int i = 0; i < 4; ++i) {
      const int rl = wid * 16 + i * 4 + (lane >> 4);
      int gr = row0 + rl;
      if (gr >= NN) gr = NN - 1;
      const int q = (lane & 15) ^ (rl & 7);
      gll16(&Xb[(size_t)gr * 128 + q * 8], &Xl[buf][rl * 128 + (lane & 15) * 8]);
    }
  };

  const int ntiles = (NN + 63) / 64;  // 1563
  int tile = vb;
  stage(0, tile);
  __syncthreads();
  int buf = 0;

  for (; tile < ntiles; tile += 128) {
    const int nxt = tile + 128;
    if (nxt < ntiles) stage(buf ^ 1, nxt);

    f32x4 acc[2][2][2];  // [mf][rel][nf] = 32 VGPR
#pragma unroll
    for (int mf = 0; mf < 2; ++mf)
#pragma unroll
      for (int rel = 0; rel < 2; ++rel)
#pragma unroll
        for (int nf = 0; nf < 2; ++nf) acc[mf][rel][nf] = (f32x4){0.f, 0.f, 0.f, 0.f};

#pragma unroll
    for (int ks = 0; ks < 4; ++ks) {
#pragma unroll
      for (int mf = 0; mf < 2; ++mf) {
        const int r = rbase + mf * 16 + lr;
        const bf16x8 a =
            *(const bf16x8*)&Xl[buf][r * 128 + (((ks * 4 + lg) ^ (lr & 7)) << 3)];
#pragma unroll
        for (int rel = 0; rel < 2; ++rel)
#pragma unroll
          for (int nf = 0; nf < 2; ++nf)
            acc[mf][rel][nf] = __builtin_amdgcn_mfma_f32_16x16x32_bf16(a, bw[rel][nf][ks], acc[mf][rel][nf], 0, 0, 0);
      }
    }

    const int row0 = tile * 64;
#pragma unroll
    for (int mf = 0; mf < 2; ++mf) {
#pragma unroll
      for (int i = 0; i < 4; ++i) {
        const int row = row0 + rbase + mf * 16 + lg * 4 + i;
        if (row < NN) {
#pragma unroll
          for (int nf = 0; nf < 2; ++nf) {
            H0[(size_t)row * 64 + cbase + nf * 16 + lr] = f2bf(acc[mf][0][nf][i]);
            H1[(size_t)row * 64 + cbase + nf * 16 + lr] = f2bf(acc[mf][1][nf][i]);
          }
        }
      }
    }
    __syncthreads();
    buf ^= 1;
  }
}

// ---------------------------------------------------------------- phase B (R10 verbatim): gemm1 || count
__global__ __launch_bounds__(256, 2) void phaseB_k(const int* __restrict__ edges,
                                                   const unsigned short* __restrict__ xb,
                                                   const unsigned short* __restrict__ Wt1,
                                                   unsigned short* __restrict__ H,
                                                   int* __restrict__ cnt_out,
                                                   int* __restrict__ cnt_in) {
  __shared__ unsigned short Xl[2][64 * 128];  // 32 KB
  const int bid = blockIdx.x;
  if (bid < GEMMB) {
    const int z = bid >> 7;
    gemm_core<128>(xb, Wt1 + (size_t)z * 128 * 128, H + (size_t)z * NN * 128, bid & 127, Xl);
    return;
  }
  const int idx = bid - GEMMB;
  const int r = idx / 625;
  const int e = (idx - r * 625) * 256 + threadIdx.x;
  const int s = edges[(size_t)r * 2 * NE + e];
  const int d = edges[(size_t)r * 2 * NE + NE + e];
  atomicAdd(&cnt_out[(size_t)r * NN + s], 1);
  atomicAdd(&cnt_in[(size_t)r * NN + d], 1);
}

// ---------------------------------------------------------------- layer-2 dual GEMM
__global__ __launch_bounds__(256, 2) void gemm_dual_k(const unsigned short* __restrict__ Xb,
                                                      const unsigned short* __restrict__ Wt,
                                                      unsigned short* __restrict__ H) {
  __shared__ unsigned short Xl[2][64 * 128];
  const int zp = blockIdx.z;
  gemm_dual_core64(Xb,
                   Wt + (size_t)(2 * zp) * 64 * 128,
                   Wt + (size_t)(2 * zp + 1) * 64 * 128,
                   H + (size_t)(2 * zp) * NN * 64,
                   H + (size_t)(2 * zp + 1) * NN * 64,
                   blockIdx.x, Xl);
}

// ---------------------------------------------------------------- scans (verbatim)
__global__ __launch_bounds__(256) void scan1_k(const int* __restrict__ cnt_in,
                                               int* __restrict__ excl,
                                               int* __restrict__ bsum) {
  const int b = blockIdx.x, t = threadIdx.x;
  const int base = b * SCAN_B;
  int v[4]; int tl = 0;
#pragma unroll
  for (int i = 0; i < 4; ++i) {
    const int idx = base + t * 4 + i;
    int c = 0;
    if (idx < NN) {
      c = cnt_in[idx] + cnt_in[NN + idx] + cnt_in[2 * NN + idx] + cnt_in[3 * NN + idx];
    }
    v[i] = c;
    tl += c;
  }
  __shared__ int sm[256];
  sm[t] = tl;
  __syncthreads();
  for (int off = 1; off < 256; off <<= 1) {
    const int x = (t >= off) ? sm[t - off] : 0;
    __syncthreads();
    sm[t] += x;
    __syncthreads();
  }
  const int incl = sm[t];
  int run = incl - tl;
#pragma unroll
  for (int i = 0; i < 4; ++i) {
    const int idx = base + t * 4 + i;
    if (idx < NN) excl[idx] = run;
    run += v[i];
  }
  if (t == 255) bsum[b] = incl;
}

__global__ __launch_bounds__(128) void scan2_k(int* __restrict__ bsum, int nb) {
  const int t = threadIdx.x;
  __shared__ int sm[128];
  const int v = (t < nb) ? bsum[t] : 0;
  sm[t] = v;
  __syncthreads();
  for (int off = 1; off < 128; off <<= 1) {
    const int x = (t >= off) ? sm[t - off] : 0;
    __syncthreads();
    sm[t] += x;
    __syncthreads();
  }
  if (t < nb) bsum[t] = sm[t] - v;
}

// scan3 + rs merged
__global__ __launch_bounds__(256) void scan3rs_k(const int* __restrict__ cnt,
                                                 float* __restrict__ rs,
                                                 const int* __restrict__ bsum,
                                                 int* __restrict__ row_ptr,
                                                 int* __restrict__ cursor) {
  const int bid = blockIdx.x, t = threadIdx.x;
  if (bid < 3125) {
    const int i = bid * 256 + t;
    rs[i] = rsqrtf(fmaxf((float)cnt[i], 1.0f));
  } else {
    const int i = (bid - 3125) * 256 + t;
    if (i < NN) {
      const int v = cursor[i] + bsum[i / SCAN_B];  // cursor holds excl from scan1
      row_ptr[i] = v;
      cursor[i] = v;
    }
    if (i == 0) row_ptr[NN] = NR * NE;
  }
}

// ---------------------------------------------------------------- fill (combined edge weight)
__global__ __launch_bounds__(256) void fill_k(const int* __restrict__ edges,
                                              const float* __restrict__ rs_out,
                                              const float* __restrict__ rs_in,
                                              int* __restrict__ cursor,
                                              int2* __restrict__ csr) {
  const int r = blockIdx.y;
  const int e = blockIdx.x * 256 + threadIdx.x;
  if (e >= NE) return;
  const int s = edges[(size_t)r * 2 * NE + e];
  const int d = edges[(size_t)r * 2 * NE + NE + e];
  const int pos = atomicAdd(&cursor[d], 1);
  const float w = rs_in[(size_t)r * NN + d] * rs_out[(size_t)r * NN + s];
  csr[pos] = make_int2(r * NN + s, __float_as_int(w));
}

// ---------------------------------------------------------------- gathers (R10-proven shapes)
__global__ __launch_bounds__(256) void gather1_k(const unsigned short* __restrict__ H,
                                                 const int* __restrict__ row_ptr,
                                                 const int2* __restrict__ csr,
                                                 const float* __restrict__ bs1,
                                                 unsigned short* __restrict__ h1b) {
  const int node = blockIdx.x * 4 + (threadIdx.x >> 6);
  const int lane = threadIdx.x & 63;
  if (node >= NN) return;
  const int g  = lane >> 4;
  const int fl = lane & 15;

  float acc[8];
#pragma unroll
  for (int j = 0; j < 8; ++j) acc[j] = 0.f;

  const int beg = row_ptr[node];
  const int end = row_ptr[node + 1];
  for (int e = beg + g; e < end; e += 4) {
    const int2 p = csr[e];
    const float w = __int_as_float(p.y);
    const bf16x8 h = *(const bf16x8*)&H[(size_t)p.x * 128 + fl * 8];
#pragma unroll
    for (int j = 0; j < 8; ++j)
      acc[j] = fmaf(bf2f((unsigned short)h[j]), w, acc[j]);
  }
#pragma unroll
  for (int j = 0; j < 8; ++j) {
    acc[j] += __shfl_xor(acc[j], 16);
    acc[j] += __shfl_xor(acc[j], 32);
  }
  if (g == 0) {
    const float4 c0 = *(const float4*)&bs1[fl * 8];
    const float4 c1 = *(const float4*)&bs1[fl * 8 + 4];
    unsigned short o[8];
    o[0] = f2bf(fmaxf(acc[0] + c0.x, 0.f));
    o[1] = f2bf(fmaxf(acc[1] + c0.y, 0.f));
    o[2] = f2bf(fmaxf(acc[2] + c0.z, 0.f));
    o[3] = f2bf(fmaxf(acc[3] + c0.w, 0.f));
    o[4] = f2bf(fmaxf(acc[4] + c1.x, 0.f));
    o[5] = f2bf(fmaxf(acc[5] + c1.y, 0.f));
    o[6] = f2bf(fmaxf(acc[6] + c1.z, 0.f));
    o[7] = f2bf(fmaxf(acc[7] + c1.w, 0.f));
    *(bf16x8*)&h1b[(size_t)node * 128 + fl * 8] = *(bf16x8*)o;
  }
}

__global__ __launch_bounds__(256) void gather2_k(const unsigned short* __restrict__ H,
                                                 const int* __restrict__ row_ptr,
                                                 const int2* __restrict__ csr,
                                                 const float* __restrict__ bs2,
                                                 float* __restrict__ out) {
  const int node = blockIdx.x * 4 + (threadIdx.x >> 6);
  const int lane = threadIdx.x & 63;
  if (node >= NN) return;
  const int g  = lane >> 3;
  const int fl = lane & 7;

  float acc[8];
#pragma unroll
  for (int j = 0; j < 8; ++j) acc[j] = 0.f;

  const int beg = row_ptr[node];
  const int end = row_ptr[node + 1];
  for (int e = beg + g; e < end; e += 8) {
    const int2 p = csr[e];
    const float w = __int_as_float(p.y);
    const bf16x8 h = *(const bf16x8*)&H[(size_t)p.x * 64 + fl * 8];
#pragma unroll
    for (int j = 0; j < 8; ++j)
      acc[j] = fmaf(bf2f((unsigned short)h[j]), w, acc[j]);
  }
#pragma unroll
  for (int j = 0; j < 8; ++j) {
    acc[j] += __shfl_xor(acc[j], 8);
    acc[j] += __shfl_xor(acc[j], 16);
    acc[j] += __shfl_xor(acc[j], 32);
  }
  if (g == 0) {
    const float4 c0 = *(const float4*)&bs2[fl * 8];
    const float4 c1 = *(const float4*)&bs2[fl * 8 + 4];
    float4 o0, o1;
    o0.x = acc[0] + c0.x; o0.y = acc[1] + c0.y; o0.z = acc[2] + c0.z; o0.w = acc[3] + c0.w;
    o1.x = acc[4] + c1.x; o1.y = acc[5] + c1.y; o1.z = acc[6] + c1.z; o1.w = acc[7] + c1.w;
    *(float4*)&out[(size_t)node * 64 + fl * 8]     = o0;
    *(float4*)&out[(size_t)node * 64 + fl * 8 + 4] = o1;
  }
}

// ---------------------------------------------------------------- launch
extern "C" void kernel_launch(void* const* d_in, const int* in_sizes, int n_in,
                              void* d_out, int out_size, void* d_ws, size_t ws_size,
                              hipStream_t stream) {
  const float* x     = (const float*)d_in[0];
  const int*   edges = (const int*)d_in[1];
  const float* W1    = (const float*)d_in[2];
  const float* b1    = (const float*)d_in[3];
  const float* W2    = (const float*)d_in[4];
  const float* b2    = (const float*)d_in[5];
  float* out = (float*)d_out;

  // ---- workspace layout (R10-proven footprint)
  unsigned short* xb   = (unsigned short*)d_ws;            // NN*128 bf16
  unsigned short* h1b  = xb;                               // reuse after layer1 GEMM
  unsigned short* Hbuf = xb + (size_t)NN * 128;            // NR*NN*128 bf16
  unsigned short* Wt1  = Hbuf + (size_t)NR * NN * 128;     // NR*128*128 bf16
  unsigned short* Wt2  = Wt1 + (size_t)NR * 128 * 128;     // NR*64*128 bf16
  float* rs_out = (float*)(Wt2 + (size_t)NR * 64 * 128);   // NR*NN
  float* rs_in  = rs_out + (size_t)NR * NN;                // NR*NN
  int* cnt_out  = (int*)(rs_in + (size_t)NR * NN);         // NR*NN
  int* cnt_in   = cnt_out + (size_t)NR * NN;               // NR*NN
  int* row_ptr  = cnt_in + (size_t)NR * NN;                // NN+1
  int* cursor   = row_ptr + (NN + 1);                      // NN
  int* bsum     = cursor + NN;                             // 128
  float* bs1    = (float*)(bsum + 128);                    // 128
  float* bs2    = bs1 + 128;                               // 64
  int2* csr     = (int2*)(bs2 + 64);                       // NR*NE int2

  const int nb = (NN + SCAN_B - 1) / SCAN_B;  // 98

  // A) streaming prep: zero counters + cvtx + cvtw1 + cvtw2 + bias sums
  phaseA_k<<<A_NBLK, 256, 0, stream>>>(x, W1, W2, b1, b2, cnt_out, xb, Wt1, Wt2, bs1, bs2);
  // B) layer-1 GEMM (unscaled) co-resident with degree-count atomics (proven 72 µs)
  phaseB_k<<<GEMMB + 2500, 256, 0, stream>>>(edges, xb, Wt1, Hbuf, cnt_out, cnt_in);
  // C) scans + rs arrays
  scan1_k<<<nb, 256, 0, stream>>>(cnt_in, cursor /*excl temp*/, bsum);
  scan2_k<<<1, 128, 0, stream>>>(bsum, nb);
  scan3rs_k<<<3125 + (NN + 255) / 256, 256, 0, stream>>>(cnt_out, rs_out, bsum, row_ptr, cursor);
  // D) CSR fill with combined edge weights
  fill_k<<<dim3((NE + 255) / 256, NR), 256, 0, stream>>>(edges, rs_out, rs_in, cursor, csr);
  // E) gather+bias+relu -> h1b
  gather1_k<<<(NN + 3) / 4, 256, 0, stream>>>(Hbuf, row_ptr, csr, bs1, h1b);
  // F) layer-2 dual GEMM (register-safe at NOUT=64; h1b read 2x not 4x)
  gemm_dual_k<<<dim3(128, 1, 2), 256, 0, stream>>>(h1b, Wt2, Hbuf);
  // G) gather+bias -> out
  gather2_k<<<(NN + 3) / 4, 256, 0, stream>>>(Hbuf, row_ptr, csr, bs2, out);
}